// Round 10
// baseline (351.844 us; speedup 1.0000x reference)
//
#include <hip/hip_runtime.h>
#include <cfloat>

#define BB   32
#define VV   2048
#define KNB  40
#define FIN  64
#define DD   4
#define PP   64
#define NN   (BB*VV)           // 65536

static __device__ __forceinline__ float fast_tanh(float z) {
    z = fminf(fmaxf(z, -15.f), 15.f);
    float e = __expf(2.f * z);
    return (e - 1.f) / (e + 1.f);
}

// ---------------------------------------------------------------------------
// Kernel 1: coords = x@W_s + b_s (N x 4), feats = x@W_f + b_f (N x 64)
// Tiled GEMM, 64 rows/block, Xs transposed, 4x4 micro-tile. (passing)
// ---------------------------------------------------------------------------
__global__ __launch_bounds__(256) void k_embed(
    const float* __restrict__ x, const float* __restrict__ Ws,
    const float* __restrict__ bs, const float* __restrict__ Wf,
    const float* __restrict__ bf, float* __restrict__ coords,
    float* __restrict__ feats)
{
    __shared__ float Xs[64][68];
    __shared__ float Wfs[64][64];
    __shared__ float Wss[64][4];
    const int tid  = threadIdx.x;
    const int row0 = blockIdx.x * 64;

    #pragma unroll
    for (int i = 0; i < 4; ++i) {
        const int idx = tid + i * 256;
        const int r   = idx >> 4;
        const int k4  = (idx & 15) << 2;
        float4 v = *(const float4*)(x + (size_t)(row0 + r) * FIN + k4);
        Xs[k4+0][r] = v.x; Xs[k4+1][r] = v.y; Xs[k4+2][r] = v.z; Xs[k4+3][r] = v.w;
        ((float4*)Wfs)[idx] = ((const float4*)Wf)[idx];
    }
    if (tid < 64) *(float4*)Wss[tid] = ((const float4*)Ws)[tid];
    __syncthreads();

    const int tx = tid & 15;
    const int ty = tid >> 4;
    float acc[4][4] = {};
    #pragma unroll 16
    for (int k = 0; k < 64; ++k) {
        float4 a = *(const float4*)&Xs[k][ty * 4];
        float4 b = *(const float4*)&Wfs[k][tx * 4];
        acc[0][0] += a.x*b.x; acc[0][1] += a.x*b.y; acc[0][2] += a.x*b.z; acc[0][3] += a.x*b.w;
        acc[1][0] += a.y*b.x; acc[1][1] += a.y*b.y; acc[1][2] += a.y*b.z; acc[1][3] += a.y*b.w;
        acc[2][0] += a.z*b.x; acc[2][1] += a.z*b.y; acc[2][2] += a.z*b.z; acc[2][3] += a.z*b.w;
        acc[3][0] += a.w*b.x; acc[3][1] += a.w*b.y; acc[3][2] += a.w*b.z; acc[3][3] += a.w*b.w;
    }
    const float4 bfv = *(const float4*)(bf + tx * 4);
    const float ar[4] = {bfv.x, bfv.y, bfv.z, bfv.w};
    #pragma unroll
    for (int i = 0; i < 4; ++i) {
        float4 o = { acc[i][0] + ar[0], acc[i][1] + ar[1],
                     acc[i][2] + ar[2], acc[i][3] + ar[3] };
        *(float4*)(feats + (size_t)(row0 + ty * 4 + i) * PP + tx * 4) = o;
    }

    const int cr = tid >> 2, cc = tid & 3;
    float ca = bs[cc];
    #pragma unroll 16
    for (int k = 0; k < 64; ++k) ca += Xs[k][cr] * Wss[k][cc];
    coords[(size_t)(row0 + cr) * DD + cc] = ca;
}

// ---------------------------------------------------------------------------
// Kernel 2: top-40 KNN + weighted max/mean pooling.
// R8/R9 BUG FOUND: fallback bins were width 8 over [0,1024). When a row
// triggers fallback (count(d2<2) < 40) but has close companions (d2 ~ 0.1,
// weight ~ e^-1), bin 0 = [0,8) could become the boundary bin (g1=0) and
// first-come region-B could DROP those companions -> O(1) corruption.
// SAFETY INVARIANT (what made R7's fallback correct): fallback bin width
// <= attempt-0 range, so fallback implies 40th >= hi0 implies g1 >= 1
// implies ALL d2 < hi0 land in exact region A. Fix: fallback scale=0.5
// (width-2 bins, [0,256)). Boundary-bin freedom then only touches
// weights <= e^-20.
// Everything else = R9: 128-bin attempt-0 hist [0,2) w=1/64, dual-mask
// collect (exactly 40 real slots), hoisted exp, 4-wide 10-iter pooling,
// barrier-free per-wave after the cpos stage.
// ---------------------------------------------------------------------------
__global__ __launch_bounds__(256) void k_knn(
    const float* __restrict__ coords, const float* __restrict__ feats,
    float* __restrict__ collected)
{
    __shared__ float4 cpos[VV];           // 32 KB
    __shared__ int    hist[4][128];       //  2 KB (per-wave)
    __shared__ float2 candP[4][KNB];      //  1.25 KB (per-wave): (w|d2, idx)

    const int tid   = threadIdx.x;
    const int lane  = tid & 63;
    const int w     = tid >> 6;
    const int batch = blockIdx.x >> 7;     // 128 blocks of 16 rows per batch
    const int chunk = blockIdx.x & 127;
    const float* cb = coords + (size_t)batch * VV * DD;
    const float* fb = feats  + (size_t)batch * VV * PP;

    for (int i = tid; i < VV; i += 256) cpos[i] = ((const float4*)cb)[i];
    __syncthreads();                       // the only barrier

    for (int rr = 0; rr < 4; ++rr) {
        const int v = (chunk << 4) + (w << 2) + rr;
        const float4 cv = cpos[v];

        // ---- distances once, cached in VGPRs (d2f[k] <-> i = lane + 64k) ----
        float d2f[32];
        #pragma unroll
        for (int j = 0; j < 16; ++j) {
            float4 c0 = cpos[lane + (j << 6)];
            float4 c1 = cpos[lane + (j << 6) + 1024];
            float ax = cv.x - c0.x, ay = cv.y - c0.y, az = cv.z - c0.z, aw = cv.w - c0.w;
            float bx = cv.x - c1.x, by = cv.y - c1.y, bz = cv.z - c1.z, bw = cv.w - c1.w;
            d2f[j]      = ax*ax + ay*ay + az*az + aw*aw;
            d2f[j + 16] = bx*bx + by*by + bz*bz + bw*bw;
        }
        if (lane == (v & 63)) d2f[v >> 6] = FLT_MAX;   // self -> sentinel

        // ---- predicated 128-bin histogram + scan ----
        // attempt 0: [0,2) w=1/64; attempt 1: [0,256) w=2 (width <= hi0: safe).
        float scale = 64.f, hi = 2.f;
        int g1 = 127, nb1 = 0;
        for (int attempt = 0; attempt < 2; ++attempt) {
            ((int2*)hist[w])[lane] = make_int2(0, 0);   // per-wave: DS ops in order
            #pragma unroll
            for (int k = 0; k < 32; ++k) {
                const float d2 = d2f[k];
                if (d2 < hi)
                    atomicAdd(&hist[w][(int)(d2 * scale)], 1);  // exact pow2 scale
            }
            const int2 hv = ((const int2*)hist[w])[lane];
            const int local = hv.x + hv.y;
            int incl = local;
            #pragma unroll
            for (int off = 1; off < 64; off <<= 1) {
                int t = __shfl_up(incl, off);
                if (lane >= off) incl += t;
            }
            const int total = __shfl(incl, 63);
            const int excl  = incl - local;
            const bool pred = (excl < KNB) && (incl >= KNB);
            unsigned long long m = __ballot(pred);
            const int src = (m == 0ull) ? 0 : (__ffsll(m) - 1);
            int gg = 0, nnb = 0;
            if (pred) {
                const bool inFirst = (excl + hv.x >= KNB);
                gg  = (lane << 1) + (inFirst ? 0 : 1);
                nnb = inFirst ? excl : (excl + hv.x);
            }
            g1  = __shfl(gg, src);
            nb1 = __shfl(nnb, src);
            if (total >= KNB) break;
            scale = 0.5f; hi = 256.f;      // FIX: width-2 fallback (was width-8)
        }
        // bin(d2) < g1 <=> d2 < g1/scale ; bin == g1 <=> flo <= d2 < fhi (exact pow2)
        const float flo = (float)g1 / scale;
        const float fhi = (float)(g1 + 1) / scale;

        // ---- dual-mask collect: exactly KNB real slots ----
        unsigned int maskA = 0u, maskB = 0u;
        #pragma unroll
        for (int k = 0; k < 32; ++k) {
            const float d2 = d2f[k];
            if (d2 < flo) maskA |= (1u << k);
            else if (d2 < fhi) maskB |= (1u << k);
        }
        const int cA = __popc(maskA), cB = __popc(maskB);
        int packed = cA | (cB << 16);            // sums fit 16 bits each
        int incl2 = packed;
        #pragma unroll
        for (int off = 1; off < 64; off <<= 1) {
            int t = __shfl_up(incl2, off);
            if (lane >= off) incl2 += t;
        }
        const int excl2 = incl2 - packed;
        int baseA = excl2 & 0xFFFF;              // region A: [0, nb1)  (exact)
        int baseB = nb1 + (excl2 >> 16);         // region B: [nb1, 40), first-come
        while (maskA) {
            const int b = __ffs(maskA) - 1; maskA &= maskA - 1;
            candP[w][baseA++] = make_float2(d2f[b], __int_as_float(lane + (b << 6)));
        }
        while (maskB && baseB < KNB) {
            const int b = __ffs(maskB) - 1; maskB &= maskB - 1;
            candP[w][baseB++] = make_float2(d2f[b], __int_as_float(lane + (b << 6)));
        }

        // ---- hoisted weight: one exp per slot (lanes 0..39), stash back ----
        if (lane < KNB) {
            float2 p = candP[w][lane];
            candP[w][lane] = make_float2(__expf(-10.f * p.x), p.y);
        }

        // ---- 4-wide pooling: 4 neighbor-subslots x 16 col-groups, 10 iters ----
        const int ng = lane >> 4;          // neighbor subslot 0..3
        const int cg = lane & 15;          // col group: cols cg*4..+3
        float4 mx = make_float4(-FLT_MAX, -FLT_MAX, -FLT_MAX, -FLT_MAX);
        float4 sm = make_float4(0.f, 0.f, 0.f, 0.f);
        #pragma unroll
        for (int t = 0; t < KNB / 4; ++t) {          // constant 10 — all real slots
            float2 p = candP[w][(t << 2) + ng];
            const float* fp = fb + ((size_t)__float_as_int(p.y) << 6) + (cg << 2);
            float4 f = *(const float4*)fp;
            float4 nv = make_float4(f.x * p.x, f.y * p.x, f.z * p.x, f.w * p.x);
            mx.x = fmaxf(mx.x, nv.x); mx.y = fmaxf(mx.y, nv.y);
            mx.z = fmaxf(mx.z, nv.z); mx.w = fmaxf(mx.w, nv.w);
            sm.x += nv.x; sm.y += nv.y; sm.z += nv.z; sm.w += nv.w;
        }
        #pragma unroll
        for (int off = 16; off <= 32; off <<= 1) {
            mx.x = fmaxf(mx.x, __shfl_xor(mx.x, off));
            mx.y = fmaxf(mx.y, __shfl_xor(mx.y, off));
            mx.z = fmaxf(mx.z, __shfl_xor(mx.z, off));
            mx.w = fmaxf(mx.w, __shfl_xor(mx.w, off));
            sm.x += __shfl_xor(sm.x, off);
            sm.y += __shfl_xor(sm.y, off);
            sm.z += __shfl_xor(sm.z, off);
            sm.w += __shfl_xor(sm.w, off);
        }
        float* outp = collected + ((size_t)(batch * VV + v) << 7);
        if (lane < 16) {
            *(float4*)(outp + (cg << 2)) = mx;
        } else if (lane < 32) {
            float4 o = make_float4(sm.x * (1.f / KNB), sm.y * (1.f / KNB),
                                   sm.z * (1.f / KNB), sm.w * (1.f / KNB));
            *(float4*)(outp + PP + (cg << 2)) = o;
        }
    }
}

// ---------------------------------------------------------------------------
// Kernel 3: out = tanh(concat(x, collected) @ W_out + b_out), (N x 192)@(192 x 128)
// A tile staged transposed As[kk][r] -> one ds_read_b128 per kk. (passing)
// ---------------------------------------------------------------------------
__global__ __launch_bounds__(256) void k_out(
    const float* __restrict__ x, const float* __restrict__ collected,
    const float* __restrict__ Wout, const float* __restrict__ bout,
    float* __restrict__ out)
{
    __shared__ float As[16][68];   // [kk][r], +4 pad
    __shared__ float Bs[16][128];
    const int tid = threadIdx.x;
    const int tx  = tid & 15;
    const int ty  = tid >> 4;
    const int row0 = blockIdx.x * 64;

    float acc[4][8];
    #pragma unroll
    for (int i = 0; i < 4; ++i)
        #pragma unroll
        for (int j = 0; j < 8; ++j) acc[i][j] = 0.f;

    for (int k0 = 0; k0 < 192; k0 += 16) {
        {
            const int r   = tid >> 2;
            const int kk4 = (tid & 3) << 2;
            const float* src = (k0 < 64)
                ? (x + (size_t)(row0 + r) * FIN + (k0 + kk4))
                : (collected + (size_t)(row0 + r) * 128 + (k0 - 64 + kk4));
            float4 v = *(const float4*)src;
            As[kk4+0][r] = v.x; As[kk4+1][r] = v.y;
            As[kk4+2][r] = v.z; As[kk4+3][r] = v.w;
        }
        #pragma unroll
        for (int rep = 0; rep < 2; ++rep) {
            const int e = (tid + rep * 256) * 4;
            const int kk = e >> 7, c = e & 127;
            *(float4*)&Bs[kk][c] = *(const float4*)(Wout + (size_t)(k0 + kk) * 128 + c);
        }
        __syncthreads();
        #pragma unroll
        for (int kk = 0; kk < 16; ++kk) {
            float4 a  = *(const float4*)&As[kk][ty * 4];
            float4 b0 = *(const float4*)&Bs[kk][tx * 4];
            float4 b1 = *(const float4*)&Bs[kk][64 + tx * 4];
            const float av[4] = {a.x, a.y, a.z, a.w};
            #pragma unroll
            for (int i = 0; i < 4; ++i) {
                acc[i][0] += av[i] * b0.x; acc[i][1] += av[i] * b0.y;
                acc[i][2] += av[i] * b0.z; acc[i][3] += av[i] * b0.w;
                acc[i][4] += av[i] * b1.x; acc[i][5] += av[i] * b1.y;
                acc[i][6] += av[i] * b1.z; acc[i][7] += av[i] * b1.w;
            }
        }
        __syncthreads();
    }

    #pragma unroll
    for (int i = 0; i < 4; ++i) {
        const int row = row0 + ty * 4 + i;
        float4 o0, o1;
        o0.x = fast_tanh(acc[i][0] + bout[tx*4+0]);
        o0.y = fast_tanh(acc[i][1] + bout[tx*4+1]);
        o0.z = fast_tanh(acc[i][2] + bout[tx*4+2]);
        o0.w = fast_tanh(acc[i][3] + bout[tx*4+3]);
        o1.x = fast_tanh(acc[i][4] + bout[64+tx*4+0]);
        o1.y = fast_tanh(acc[i][5] + bout[64+tx*4+1]);
        o1.z = fast_tanh(acc[i][6] + bout[64+tx*4+2]);
        o1.w = fast_tanh(acc[i][7] + bout[64+tx*4+3]);
        *(float4*)(out + (size_t)row * 128 + tx * 4)      = o0;
        *(float4*)(out + (size_t)row * 128 + 64 + tx * 4) = o1;
    }
}

// ---------------------------------------------------------------------------
extern "C" void kernel_launch(void* const* d_in, const int* in_sizes, int n_in,
                              void* d_out, int out_size, void* d_ws, size_t ws_size,
                              hipStream_t stream)
{
    const float* x    = (const float*)d_in[0];
    // d_in[1] = row_splits: uniform arange(B+1)*V — fixed structure, unused.
    const float* Ws   = (const float*)d_in[2];
    const float* bs   = (const float*)d_in[3];
    const float* Wf   = (const float*)d_in[4];
    const float* bf   = (const float*)d_in[5];
    const float* Wout = (const float*)d_in[6];
    const float* bout = (const float*)d_in[7];
    float* out = (float*)d_out;

    float* coords = (float*)d_ws;                                            // 1 MB
    float* feats  = (float*)((char*)d_ws + (size_t)NN * DD * sizeof(float)); // 16 MB
    float* collected = out;   // reuse d_out as scratch for pooled features

    hipLaunchKernelGGL(k_embed, dim3(NN / 64), dim3(256), 0, stream,
                       x, Ws, bs, Wf, bf, coords, feats);
    // 16 rows per block (4 waves x 4 rows) -> NN/16 = 4096 blocks
    hipLaunchKernelGGL(k_knn, dim3(NN / 16), dim3(256), 0, stream,
                       coords, feats, collected);
    hipLaunchKernelGGL(k_out, dim3(NN / 64), dim3(256), 0, stream,
                       x, collected, Wout, bout, out);
}